// Round 4
// baseline (2461.846 us; speedup 1.0000x reference)
//
#include <hip/hip_runtime.h>

// Problem dims
#define Bdim 64
#define Sdim 512
#define Vdim 30000
#define Edim 300
#define Hdim 256
#define Cdim 32
#define G4   1024     // 4*H
#define NROW 32768    // B*S
#define KQ   32       // 256 k-values / 8 per 16B chunk
#define USTAGE 3      // kq-blocks of U staged in LDS (24 k-rows = 48 KB)
#define RKQ    20     // kq-blocks of U staged in VGPRs (80 VGPRs, asm-pinned)
#define EPAIR  (Edim / 2)   // 150 f16-pairs along E
#define XLSTR  152          // padded LDS row stride (uints) for 8B alignment

// ---------- f16 helpers (store as plain ushort to avoid ABI surprises) -----
typedef _Float16 half2v __attribute__((ext_vector_type(2)));

__device__ __forceinline__ unsigned short f2h_bits(float f) {
    union { _Float16 h; unsigned short u; } v; v.h = (_Float16)f; return v.u;
}
__device__ __forceinline__ float h2f(unsigned short u) {
    union { _Float16 h; unsigned short u; } v; v.u = u; return (float)v.h;
}
__device__ __forceinline__ unsigned int pack2h(float lo, float hi) {
    return (unsigned int)f2h_bits(lo) | ((unsigned int)f2h_bits(hi) << 16);
}
__device__ __forceinline__ float sigf(float x) { return 1.0f / (1.0f + __expf(-x)); }
__device__ __forceinline__ float tanhfast(float x) { return 2.0f / (1.0f + __expf(-2.0f * x)) - 1.0f; }

// 2 MACs from packed f16 pairs, f32 accumulate (v_dot2_f32_f16 when available)
__device__ __forceinline__ float dot2(unsigned int u, unsigned int h, float acc) {
#if __has_builtin(__builtin_amdgcn_fdot2)
    union { unsigned int i; half2v h; } a, b; a.i = u; b.i = h;
    return __builtin_amdgcn_fdot2(a.h, b.h, acc, false);
#else
    acc = fmaf(h2f((unsigned short)(u & 0xffffu)), h2f((unsigned short)(h & 0xffffu)), acc);
    return fmaf(h2f((unsigned short)(u >> 16)), h2f((unsigned short)(h >> 16)), acc);
#endif
}
// 8 MACs from one 16B U chunk and one 16B h chunk (two independent chains)
__device__ __forceinline__ void dot8(float& a0, float& a1, uint4 uv, uint4 hv) {
    a0 = dot2(uv.x, hv.x, a0);
    a1 = dot2(uv.y, hv.y, a1);
    a0 = dot2(uv.z, hv.z, a0);
    a1 = dot2(uv.w, hv.w, a1);
}

// ---------- K0a: pack U (f32 [256][1024]) -> f16 chunks [2][32][1024][8] ----
__global__ __launch_bounds__(256) void k_pack_u8(
    const float* __restrict__ Uf, const float* __restrict__ Ub,
    unsigned short* __restrict__ upk8)
{
    int idx = blockIdx.x * 256 + threadIdx.x;   // 0 .. 65535
    if (idx >= 2 * KQ * 1024) return;
    int dir = idx >> 15;
    int rem = idx & 32767;
    int kq  = rem >> 10;
    int n   = rem & 1023;
    const float* U = dir ? Ub : Uf;
    unsigned int w[4];
    #pragma unroll
    for (int p = 0; p < 4; ++p)
        w[p] = pack2h(U[(8 * kq + 2 * p) * G4 + n], U[(8 * kq + 2 * p + 1) * G4 + n]);
    uint4 o = make_uint4(w[0], w[1], w[2], w[3]);
    *(uint4*)&upk8[(size_t)idx * 8] = o;
}

// ---------- K0b: pack emb f32 [V][300] -> f16 pairs [V*150] uints -----------
__global__ __launch_bounds__(256) void k_pack_emb(
    const float* __restrict__ emb, unsigned int* __restrict__ embp)
{
    int p = blockIdx.x * 256 + threadIdx.x;     // flat pair index
    if (p >= Vdim * EPAIR) return;
    float2 v = *(const float2*)&emb[(size_t)2 * p];
    embp[p] = pack2h(v.x, v.y);
}

// ---------- K0c: pack W f32 [300][1024] -> f16 k-pairs [2][150][1024] -------
__global__ __launch_bounds__(256) void k_pack_w(
    const float* __restrict__ Wf, const float* __restrict__ Wb,
    unsigned int* __restrict__ Wp)
{
    int idx = blockIdx.x * 256 + threadIdx.x;   // 0 .. 2*150*1024-1
    if (idx >= 2 * EPAIR * 1024) return;
    int dir = idx / (EPAIR * 1024);
    int rem = idx - dir * (EPAIR * 1024);
    int kp  = rem >> 10;
    int n   = rem & 1023;
    const float* W = dir ? Wb : Wf;
    Wp[idx] = pack2h(W[(2 * kp) * G4 + n], W[(2 * kp + 1) * G4 + n]);
}

// ---------- K1: xproj = emb[tokens] @ W + bias  -> f16 [2][NROW][1024] ------
// grid (NROW/32, 8), block 256. BOTH dirs per block (halves gather traffic).
// M-tile 32 (LDS 19.5KB), N-tile 128. Inner loop is v_dot2_f32_f16.
__global__ __launch_bounds__(256) void k_xproj(
    const int* __restrict__ tokens, const unsigned int* __restrict__ embp,
    const unsigned int* __restrict__ Wp,
    const float* __restrict__ bf_, const float* __restrict__ bb_,
    unsigned short* __restrict__ xp)
{
    __shared__ unsigned int xl[32 * XLSTR];    // 19456 B, f16 pairs
    const int m0  = blockIdx.x * 32;
    const int tid = threadIdx.x;

    for (int i = tid; i < 32 * EPAIR; i += 256) {
        int r = i / EPAIR, kp = i - r * EPAIR;
        int tok = tokens[m0 + r];
        xl[r * XLSTR + kp] = embp[(size_t)tok * EPAIR + kp];
    }
    __syncthreads();

    const int tx = tid & 31, ty = tid >> 5;          // ty: 8 groups of 4 rows
    const int c0 = blockIdx.y * 128 + tx;            // cols c0 + 32*j
    float bj[2][4];
    #pragma unroll
    for (int j = 0; j < 4; ++j) {
        bj[0][j] = bf_[c0 + 32 * j];
        bj[1][j] = bb_[c0 + 32 * j];
    }
    float acc[2][4][4] = {};

    for (int kp = 0; kp < EPAIR; kp += 2) {          // 150 = 75*2 exact
        uint2 xv[4];
        #pragma unroll
        for (int i = 0; i < 4; ++i)
            xv[i] = *(const uint2*)&xl[(ty * 4 + i) * XLSTR + kp];
        #pragma unroll
        for (int kk = 0; kk < 2; ++kk) {
            #pragma unroll
            for (int d = 0; d < 2; ++d) {
                const unsigned int* W = Wp + (size_t)d * EPAIR * 1024 + (kp + kk) * 1024;
                unsigned int w0 = W[c0];
                unsigned int w1 = W[c0 + 32];
                unsigned int w2 = W[c0 + 64];
                unsigned int w3 = W[c0 + 96];
                #pragma unroll
                for (int i = 0; i < 4; ++i) {
                    unsigned int xpair = kk ? xv[i].y : xv[i].x;
                    acc[d][i][0] = dot2(w0, xpair, acc[d][i][0]);
                    acc[d][i][1] = dot2(w1, xpair, acc[d][i][1]);
                    acc[d][i][2] = dot2(w2, xpair, acc[d][i][2]);
                    acc[d][i][3] = dot2(w3, xpair, acc[d][i][3]);
                }
            }
        }
    }
    #pragma unroll
    for (int d = 0; d < 2; ++d) {
        size_t base = (size_t)d * NROW * G4;
        #pragma unroll
        for (int i = 0; i < 4; ++i) {
            size_t row = (size_t)(m0 + ty * 4 + i) * G4;
            #pragma unroll
            for (int j = 0; j < 4; ++j)
                xp[base + row + c0 + 32 * j] = f2h_bits(acc[d][i][j] + bj[d][j]);
        }
    }
}

// ---------- K2: LSTM recurrence, v5 ----------------------------------------
// 128 WGs = (dir, batch), 1024 threads (16 waves/CU). Thread n owns column n:
// z[n] = xp[t][n] + sum_k h[k]*U[k][n], via v_dot2_f32_f16 on packed f16.
// U kq-blocks: [0,USTAGE) in LDS, [USTAGE,USTAGE+RKQ) ASM-PINNED in VGPRs,
// remaining 9 streamed from L2 (144 KB/step). h broadcast from LDS.
// h/c update computed redundantly by all threads (parallel tail).
__global__ __launch_bounds__(1024, 4) void k_lstm(
    const unsigned short* __restrict__ upk8,   // [2][KQ][1024][8] f16
    const unsigned short* __restrict__ xp,     // [2][NROW][1024]  f16
    unsigned short* __restrict__ hout)         // [NROW][512] f16 = [hf|hb]
{
    const int bx  = blockIdx.x;
    const int dir = bx >> 6;
    const int b   = bx & 63;
    const int n   = threadIdx.x;               // 0..1023
    const int gi  = n >> 8;                    // gate: 0=i 1=f 2=g 3=o
    const unsigned short* __restrict__ Uq = upk8 + (size_t)dir * (KQ * 1024 * 8);
    const unsigned short* __restrict__ xpd =
        xp + (size_t)dir * NROW * G4 + (size_t)b * Sdim * G4;

    __shared__ unsigned short ust[USTAGE * 1024 * 8];       // 48 KB (kq 0..2)
    __shared__ float          abuf[1024];                   // 4 KB gates
    __shared__ __align__(16) unsigned short hl[256];        // f16 h

    {   // vectorized one-time LDS stage of U kq-blocks [0,USTAGE)
        const uint4* src = (const uint4*)Uq;
        uint4*       dst = (uint4*)ust;
        for (int i = n; i < USTAGE * 1024; i += 1024) dst[i] = src[i];
    }
    // register-stage U kq-blocks [USTAGE, USTAGE+RKQ) — step-invariant.
    uint4 ur[RKQ];
    #pragma unroll
    for (int r = 0; r < RKQ; ++r)
        ur[r] = *(const uint4*)&Uq[((size_t)(USTAGE + r) * 1024 + n) * 8];
    // PIN: make values opaque so the compiler cannot sink/remat the loads
    // into the step loop (round-3 failure: VGPR capped at 64, loads sunk).
    #pragma unroll
    for (int r = 0; r < RKQ; ++r)
        asm volatile("" : "+v"(ur[r].x), "+v"(ur[r].y), "+v"(ur[r].z), "+v"(ur[r].w));

    if (n < 256) hl[n] = 0;
    float c = 0.0f;
    const int j = n & 255;
    __syncthreads();

    for (int step = 0; step < Sdim; ++step) {
        const int t = dir ? (Sdim - 1 - step) : step;
        float zx = h2f(xpd[(size_t)t * G4 + n]);   // issued early, used late
        float a0 = 0.0f, a1 = 0.0f;
        // streamed-from-L2 blocks (issue loads first; compiler pipelines)
        #pragma unroll
        for (int kq = USTAGE + RKQ; kq < KQ; ++kq) {
            uint4 uv = *(const uint4*)&Uq[((size_t)kq * 1024 + n) * 8];
            uint4 hv = *(const uint4*)&hl[kq * 8];
            dot8(a0, a1, uv, hv);
        }
        // register-staged blocks
        #pragma unroll
        for (int r = 0; r < RKQ; ++r) {
            uint4 hv = *(const uint4*)&hl[(USTAGE + r) * 8];
            dot8(a0, a1, ur[r], hv);
        }
        // LDS-staged blocks
        #pragma unroll
        for (int kq = 0; kq < USTAGE; ++kq) {
            uint4 uv = *(const uint4*)&ust[(kq * 1024 + n) * 8];
            uint4 hv = *(const uint4*)&hl[kq * 8];
            dot8(a0, a1, uv, hv);
        }
        float z = zx + a0 + a1;
        float a = (gi == 2) ? tanhfast(z) : sigf(z);
        abuf[n] = a;
        __syncthreads();               // abuf complete; all hl readers done
        // all threads redundantly update column j = n&255 (parallel tail)
        float iv = abuf[j];
        float fv = abuf[j + 256];
        float gv = abuf[j + 512];
        float ov = abuf[j + 768];
        c = fv * c + iv * gv;
        float hn = ov * tanhfast(c);
        unsigned short hb = f2h_bits(hn);
        if (n < 256) {
            hl[n] = hb;
            hout[((size_t)(b * Sdim + t)) * 512 + dir * 256 + n] = hb;
        }
        __syncthreads();               // hl ready for next step
    }
}

// ---------- K3: logits = [hf|hb] @ Wd + bd -> d_out[0:1048576] --------------
// grid 4096, block 256 = 8 rows x 32 cols. Wd staged in two 32KB halves.
__global__ __launch_bounds__(256) void k_dense(
    const unsigned short* __restrict__ hall, const float* __restrict__ Wd,
    const float* __restrict__ bd, float* __restrict__ outL)
{
    __shared__ float wl[256 * 32];    // 32 KB
    __shared__ float hlr[8 * 512];    // 16 KB
    const int r0  = blockIdx.x * 8;
    const int tid = threadIdx.x;
    for (int i = tid; i < 8 * 512; i += 256)
        hlr[i] = h2f(hall[(size_t)r0 * 512 + i]);
    const int tx = tid & 31, ty = tid >> 5;
    float acc = 0.0f;
    for (int half = 0; half < 2; ++half) {
        __syncthreads();   // prior readers done (also covers hlr stores)
        for (int i = tid; i < 256 * 32; i += 256) wl[i] = Wd[half * 8192 + i];
        __syncthreads();
        const float* hrow = hlr + ty * 512 + half * 256;
        #pragma unroll 8
        for (int k = 0; k < 256; ++k)
            acc = fmaf(hrow[k], wl[k * 32 + tx], acc);
    }
    outL[(size_t)(r0 + ty) * 32 + tx] = acc + bd[tx];
}

// ---------- K4: CRF log-likelihood + trans passthrough ----------------------
// grid 64 (one WG per batch), block 256. Lanes 0-31 own classes for the scan.
__global__ __launch_bounds__(256) void k_crf(
    const float* __restrict__ logits, const int* __restrict__ targets,
    const int* __restrict__ lengths, const float* __restrict__ trans,
    float* __restrict__ out_ll, float* __restrict__ out_trans)
{
    const int b   = blockIdx.x;
    const int tid = threadIdx.x;
    __shared__ float tT[32 * 33];     // trans transposed, padded
    __shared__ float alpha[32];
    __shared__ float red[2][256];

    if (b == 0)
        for (int i = tid; i < 1024; i += 256) out_trans[i] = trans[i];
    for (int i = tid; i < 1024; i += 256) {
        int ii = i >> 5, jj = i & 31;
        tT[jj * 33 + ii] = trans[i];
    }
    const int len = lengths[b];
    const float* lg = logits + (size_t)b * Sdim * Cdim;
    const int*   tg = targets + b * Sdim;

    float u = 0.0f, bs = 0.0f;
    for (int t = tid; t < Sdim; t += 256) {
        if (t < len) {
            u += lg[t * 32 + tg[t]];
            if (t >= 1) bs += trans[tg[t - 1] * 32 + tg[t]];
        }
    }
    red[0][tid] = u; red[1][tid] = bs;
    __syncthreads();
    for (int off = 128; off > 0; off >>= 1) {
        if (tid < off) {
            red[0][tid] += red[0][tid + off];
            red[1][tid] += red[1][tid + off];
        }
        __syncthreads();
    }

    if (tid < 32) alpha[tid] = lg[tid];
    float trow[32];
    if (tid < 32) {
        #pragma unroll
        for (int i = 0; i < 32; ++i) trow[i] = tT[tid * 33 + i];
    }
    __syncthreads();

    float lcur = 0.0f;
    if (tid < 32 && len > 1) lcur = lg[32 + tid];
    for (int t = 1; t < len; ++t) {
        float nv = 0.0f, lnxt = 0.0f;
        if (tid < 32) {
            if (t + 1 < len) lnxt = lg[(t + 1) * 32 + tid];   // prefetch
            float m = -3.0e38f;
            #pragma unroll
            for (int i = 0; i < 32; ++i) m = fmaxf(m, alpha[i] + trow[i]);
            float s = 0.0f;
            #pragma unroll
            for (int i = 0; i < 32; ++i) s += __expf(alpha[i] + trow[i] - m);
            nv = m + __logf(s) + lcur;
        }
        __syncthreads();
        if (tid < 32) alpha[tid] = nv;
        __syncthreads();
        lcur = lnxt;
    }
    if (tid == 0) {
        float m = -3.0e38f;
        for (int j = 0; j < 32; ++j) m = fmaxf(m, alpha[j]);
        float s = 0.0f;
        for (int j = 0; j < 32; ++j) s += __expf(alpha[j] - m);
        out_ll[b] = red[0][0] + red[1][0] - (m + __logf(s));
    }
}

// ---------------------------------------------------------------------------
extern "C" void kernel_launch(void* const* d_in, const int* in_sizes, int n_in,
                              void* d_out, int out_size, void* d_ws, size_t ws_size,
                              hipStream_t stream) {
    (void)in_sizes; (void)n_in; (void)out_size; (void)ws_size;
    const int*   tokens  = (const int*)d_in[0];
    const int*   lengths = (const int*)d_in[1];
    const int*   targets = (const int*)d_in[2];
    const float* emb     = (const float*)d_in[3];
    const float* Wf      = (const float*)d_in[4];
    const float* Uf      = (const float*)d_in[5];
    const float* bf_     = (const float*)d_in[6];
    const float* Wb      = (const float*)d_in[7];
    const float* Ub      = (const float*)d_in[8];
    const float* bb_     = (const float*)d_in[9];
    const float* Wd      = (const float*)d_in[10];
    const float* bd      = (const float*)d_in[11];
    const float* trans   = (const float*)d_in[12];

    float* out_logits = (float*)d_out;                 // 1048576
    float* out_ll     = out_logits + 1048576;          // 64
    float* out_trans  = out_ll + 64;                   // 1024

    // ws layout (~161 MiB, unchanged):
    //   [0, 1MB)              ushort upk8[2][32][1024][8]   (f16 U chunks)
    //   [1MB, 1MB+128MB)      ushort xp [2][NROW][1024]     (f16)
    //   [.., +32MB)           ushort hall[NROW][512]        (f16)
    // embp (18MB) + Wp (1.2MB) live INSIDE the hall region: they are only
    // needed until k_xproj finishes; k_lstm overwrites hall afterwards.
    char* ws = (char*)d_ws;
    unsigned short* upk8 = (unsigned short*)ws;
    unsigned short* xp   = (unsigned short*)(ws + (1u << 20));
    char*           hreg = ws + (1u << 20) + (size_t)2 * NROW * G4 * 2;
    unsigned short* hall = (unsigned short*)hreg;
    unsigned int*   embp = (unsigned int*)hreg;                       // 18.0 MB
    unsigned int*   Wp   = (unsigned int*)(hreg + (size_t)Vdim * EPAIR * 4); // 1.2 MB

    k_pack_u8 <<<dim3(256), dim3(256), 0, stream>>>(Uf, Ub, upk8);
    k_pack_emb<<<dim3((Vdim * EPAIR + 255) / 256), dim3(256), 0, stream>>>(emb, embp);
    k_pack_w  <<<dim3((2 * EPAIR * 1024 + 255) / 256), dim3(256), 0, stream>>>(Wf, Wb, Wp);
    k_xproj   <<<dim3(NROW / 32, 8), dim3(256), 0, stream>>>(tokens, embp, Wp, bf_, bb_, xp);
    k_lstm    <<<dim3(128), dim3(1024), 0, stream>>>(upk8, xp, hall);
    k_dense   <<<dim3(NROW / 8), dim3(256), 0, stream>>>(hall, Wd, bd, out_logits);
    k_crf     <<<dim3(64), dim3(256), 0, stream>>>(out_logits, targets, lengths, trans, out_ll, out_trans);
}

// Round 5
// 1620.840 us; speedup vs baseline: 1.5189x; 1.5189x over previous
//
#include <hip/hip_runtime.h>

// Problem dims
#define Bdim 64
#define Sdim 512
#define Vdim 30000
#define Edim 300
#define Hdim 256
#define Cdim 32
#define G4   1024     // 4*H
#define NROW 32768    // B*S
#define KQ   32       // 256 k-values / 8 per 16B chunk
#define USTAGE 9      // kq-blocks of U staged in DYNAMIC LDS (144 KB)
#define RKQ    12     // kq-blocks of U staged in VGPRs (round-2-proven, no pin)
#define EPAIR  (Edim / 2)   // 150 f16-pairs along E
#define XLSTR  152          // padded LDS row stride (uints) for 8B alignment

// ---------- f16 helpers (store as plain ushort to avoid ABI surprises) -----
typedef _Float16 half2v __attribute__((ext_vector_type(2)));

__device__ __forceinline__ unsigned short f2h_bits(float f) {
    union { _Float16 h; unsigned short u; } v; v.h = (_Float16)f; return v.u;
}
__device__ __forceinline__ float h2f(unsigned short u) {
    union { _Float16 h; unsigned short u; } v; v.u = u; return (float)v.h;
}
__device__ __forceinline__ unsigned int pack2h(float lo, float hi) {
    return (unsigned int)f2h_bits(lo) | ((unsigned int)f2h_bits(hi) << 16);
}
__device__ __forceinline__ float sigf(float x) { return 1.0f / (1.0f + __expf(-x)); }
__device__ __forceinline__ float tanhfast(float x) { return 2.0f / (1.0f + __expf(-2.0f * x)) - 1.0f; }

// 2 MACs from packed f16 pairs, f32 accumulate (v_dot2_f32_f16 when available)
__device__ __forceinline__ float dot2(unsigned int u, unsigned int h, float acc) {
#if __has_builtin(__builtin_amdgcn_fdot2)
    union { unsigned int i; half2v h; } a, b; a.i = u; b.i = h;
    return __builtin_amdgcn_fdot2(a.h, b.h, acc, false);
#else
    acc = fmaf(h2f((unsigned short)(u & 0xffffu)), h2f((unsigned short)(h & 0xffffu)), acc);
    return fmaf(h2f((unsigned short)(u >> 16)), h2f((unsigned short)(h >> 16)), acc);
#endif
}
// 8 MACs from one 16B U chunk and one 16B h chunk (two independent chains)
__device__ __forceinline__ void dot8(float& a0, float& a1, uint4 uv, uint4 hv) {
    a0 = dot2(uv.x, hv.x, a0);
    a1 = dot2(uv.y, hv.y, a1);
    a0 = dot2(uv.z, hv.z, a0);
    a1 = dot2(uv.w, hv.w, a1);
}

// ---------- K0a: pack U (f32 [256][1024]) -> f16 chunks [2][32][1024][8] ----
__global__ __launch_bounds__(256) void k_pack_u8(
    const float* __restrict__ Uf, const float* __restrict__ Ub,
    unsigned short* __restrict__ upk8)
{
    int idx = blockIdx.x * 256 + threadIdx.x;   // 0 .. 65535
    if (idx >= 2 * KQ * 1024) return;
    int dir = idx >> 15;
    int rem = idx & 32767;
    int kq  = rem >> 10;
    int n   = rem & 1023;
    const float* U = dir ? Ub : Uf;
    unsigned int w[4];
    #pragma unroll
    for (int p = 0; p < 4; ++p)
        w[p] = pack2h(U[(8 * kq + 2 * p) * G4 + n], U[(8 * kq + 2 * p + 1) * G4 + n]);
    uint4 o = make_uint4(w[0], w[1], w[2], w[3]);
    *(uint4*)&upk8[(size_t)idx * 8] = o;
}

// ---------- K0b: pack emb f32 [V][300] -> f16 pairs [V*150] uints -----------
__global__ __launch_bounds__(256) void k_pack_emb(
    const float* __restrict__ emb, unsigned int* __restrict__ embp)
{
    int p = blockIdx.x * 256 + threadIdx.x;     // flat pair index
    if (p >= Vdim * EPAIR) return;
    float2 v = *(const float2*)&emb[(size_t)2 * p];
    embp[p] = pack2h(v.x, v.y);
}

// ---------- K0c: pack W f32 [300][1024] -> f16 k-pairs [2][150][1024] -------
__global__ __launch_bounds__(256) void k_pack_w(
    const float* __restrict__ Wf, const float* __restrict__ Wb,
    unsigned int* __restrict__ Wp)
{
    int idx = blockIdx.x * 256 + threadIdx.x;   // 0 .. 2*150*1024-1
    if (idx >= 2 * EPAIR * 1024) return;
    int dir = idx / (EPAIR * 1024);
    int rem = idx - dir * (EPAIR * 1024);
    int kp  = rem >> 10;
    int n   = rem & 1023;
    const float* W = dir ? Wb : Wf;
    Wp[idx] = pack2h(W[(2 * kp) * G4 + n], W[(2 * kp + 1) * G4 + n]);
}

// ---------- K1: xproj = emb[tokens] @ W + bias  -> f16 [2][NROW][1024] ------
// grid (NROW/32, 8), block 256. BOTH dirs per block (halves gather traffic).
__global__ __launch_bounds__(256) void k_xproj(
    const int* __restrict__ tokens, const unsigned int* __restrict__ embp,
    const unsigned int* __restrict__ Wp,
    const float* __restrict__ bf_, const float* __restrict__ bb_,
    unsigned short* __restrict__ xp)
{
    __shared__ unsigned int xl[32 * XLSTR];    // 19456 B, f16 pairs
    const int m0  = blockIdx.x * 32;
    const int tid = threadIdx.x;

    for (int i = tid; i < 32 * EPAIR; i += 256) {
        int r = i / EPAIR, kp = i - r * EPAIR;
        int tok = tokens[m0 + r];
        xl[r * XLSTR + kp] = embp[(size_t)tok * EPAIR + kp];
    }
    __syncthreads();

    const int tx = tid & 31, ty = tid >> 5;          // ty: 8 groups of 4 rows
    const int c0 = blockIdx.y * 128 + tx;            // cols c0 + 32*j
    float bj[2][4];
    #pragma unroll
    for (int j = 0; j < 4; ++j) {
        bj[0][j] = bf_[c0 + 32 * j];
        bj[1][j] = bb_[c0 + 32 * j];
    }
    float acc[2][4][4] = {};

    for (int kp = 0; kp < EPAIR; kp += 2) {          // 150 = 75*2 exact
        uint2 xv[4];
        #pragma unroll
        for (int i = 0; i < 4; ++i)
            xv[i] = *(const uint2*)&xl[(ty * 4 + i) * XLSTR + kp];
        #pragma unroll
        for (int kk = 0; kk < 2; ++kk) {
            #pragma unroll
            for (int d = 0; d < 2; ++d) {
                const unsigned int* W = Wp + (size_t)d * EPAIR * 1024 + (kp + kk) * 1024;
                unsigned int w0 = W[c0];
                unsigned int w1 = W[c0 + 32];
                unsigned int w2 = W[c0 + 64];
                unsigned int w3 = W[c0 + 96];
                #pragma unroll
                for (int i = 0; i < 4; ++i) {
                    unsigned int xpair = kk ? xv[i].y : xv[i].x;
                    acc[d][i][0] = dot2(w0, xpair, acc[d][i][0]);
                    acc[d][i][1] = dot2(w1, xpair, acc[d][i][1]);
                    acc[d][i][2] = dot2(w2, xpair, acc[d][i][2]);
                    acc[d][i][3] = dot2(w3, xpair, acc[d][i][3]);
                }
            }
        }
    }
    #pragma unroll
    for (int d = 0; d < 2; ++d) {
        size_t base = (size_t)d * NROW * G4;
        #pragma unroll
        for (int i = 0; i < 4; ++i) {
            size_t row = (size_t)(m0 + ty * 4 + i) * G4;
            #pragma unroll
            for (int j = 0; j < 4; ++j)
                xp[base + row + c0 + 32 * j] = f2h_bits(acc[d][i][j] + bj[d][j]);
        }
    }
}

// ---------- K2: LSTM recurrence, v6 ----------------------------------------
// 128 WGs = (dir, batch), 1024 threads (16 waves/CU). Thread n owns column n.
// U kq-blocks: [0,USTAGE=9) in 144KB DYNAMIC LDS, [9,21) in VGPRs (RKQ=12,
// round-2-proven), remaining 11 streamed from L2 (176 KB/step).
// Round-2 structure restored: no asm pin, serial n<256 tail.
__global__ __launch_bounds__(1024, 4) void k_lstm(
    const unsigned short* __restrict__ upk8,   // [2][KQ][1024][8] f16
    const unsigned short* __restrict__ xp,     // [2][NROW][1024]  f16
    unsigned short* __restrict__ hout)         // [NROW][512] f16 = [hf|hb]
{
    const int bx  = blockIdx.x;
    const int dir = bx >> 6;
    const int b   = bx & 63;
    const int n   = threadIdx.x;               // 0..1023
    const int gi  = n >> 8;                    // gate: 0=i 1=f 2=g 3=o
    const unsigned short* __restrict__ Uq = upk8 + (size_t)dir * (KQ * 1024 * 8);
    const unsigned short* __restrict__ xpd =
        xp + (size_t)dir * NROW * G4 + (size_t)b * Sdim * G4;

    __shared__ float          abuf[1024];                   // 4 KB gates
    __shared__ __align__(16) unsigned short hl[256];        // f16 h
    extern __shared__ __align__(16) unsigned short ust[];   // 144 KB (kq 0..8)

    {   // vectorized one-time LDS stage of U kq-blocks [0,USTAGE)
        const uint4* src = (const uint4*)Uq;
        uint4*       dst = (uint4*)ust;
        for (int i = n; i < USTAGE * 1024; i += 1024) dst[i] = src[i];
    }
    // register-stage U kq-blocks [USTAGE, USTAGE+RKQ) — step-invariant
    uint4 ur[RKQ];
    #pragma unroll
    for (int r = 0; r < RKQ; ++r)
        ur[r] = *(const uint4*)&Uq[((size_t)(USTAGE + r) * 1024 + n) * 8];

    if (n < 256) hl[n] = 0;
    float c = 0.0f;
    __syncthreads();

    for (int step = 0; step < Sdim; ++step) {
        const int t = dir ? (Sdim - 1 - step) : step;
        float zx = h2f(xpd[(size_t)t * G4 + n]);   // issued early, used late
        float a0 = 0.0f, a1 = 0.0f;
        // streamed-from-L2 blocks (issue loads first; compiler pipelines)
        #pragma unroll
        for (int kq = USTAGE + RKQ; kq < KQ; ++kq) {
            uint4 uv = *(const uint4*)&Uq[((size_t)kq * 1024 + n) * 8];
            uint4 hv = *(const uint4*)&hl[kq * 8];
            dot8(a0, a1, uv, hv);
        }
        // register-staged blocks
        #pragma unroll
        for (int r = 0; r < RKQ; ++r) {
            uint4 hv = *(const uint4*)&hl[(USTAGE + r) * 8];
            dot8(a0, a1, ur[r], hv);
        }
        // LDS-staged blocks
        #pragma unroll
        for (int kq = 0; kq < USTAGE; ++kq) {
            uint4 uv = *(const uint4*)&ust[(kq * 1024 + n) * 8];
            uint4 hv = *(const uint4*)&hl[kq * 8];
            dot8(a0, a1, uv, hv);
        }
        float z = zx + a0 + a1;
        float a = (gi == 2) ? tanhfast(z) : sigf(z);
        abuf[n] = a;
        __syncthreads();               // abuf complete; all hl readers done
        if (n < 256) {
            float iv = abuf[n];
            float fv = abuf[n + 256];
            float gv = abuf[n + 512];
            float ov = abuf[n + 768];
            c = fv * c + iv * gv;
            float hn = ov * tanhfast(c);
            unsigned short hb = f2h_bits(hn);
            hl[n] = hb;
            hout[((size_t)(b * Sdim + t)) * 512 + dir * 256 + n] = hb;
        }
        __syncthreads();               // hl ready for next step
    }
}

// ---------- K3: logits = [hf|hb] @ Wd + bd -> d_out[0:1048576] --------------
__global__ __launch_bounds__(256) void k_dense(
    const unsigned short* __restrict__ hall, const float* __restrict__ Wd,
    const float* __restrict__ bd, float* __restrict__ outL)
{
    __shared__ float wl[256 * 32];    // 32 KB
    __shared__ float hlr[8 * 512];    // 16 KB
    const int r0  = blockIdx.x * 8;
    const int tid = threadIdx.x;
    for (int i = tid; i < 8 * 512; i += 256)
        hlr[i] = h2f(hall[(size_t)r0 * 512 + i]);
    const int tx = tid & 31, ty = tid >> 5;
    float acc = 0.0f;
    for (int half = 0; half < 2; ++half) {
        __syncthreads();   // prior readers done (also covers hlr stores)
        for (int i = tid; i < 256 * 32; i += 256) wl[i] = Wd[half * 8192 + i];
        __syncthreads();
        const float* hrow = hlr + ty * 512 + half * 256;
        #pragma unroll 8
        for (int k = 0; k < 256; ++k)
            acc = fmaf(hrow[k], wl[k * 32 + tx], acc);
    }
    outL[(size_t)(r0 + ty) * 32 + tx] = acc + bd[tx];
}

// ---------- K4: CRF log-likelihood + trans passthrough ----------------------
__global__ __launch_bounds__(256) void k_crf(
    const float* __restrict__ logits, const int* __restrict__ targets,
    const int* __restrict__ lengths, const float* __restrict__ trans,
    float* __restrict__ out_ll, float* __restrict__ out_trans)
{
    const int b   = blockIdx.x;
    const int tid = threadIdx.x;
    __shared__ float tT[32 * 33];     // trans transposed, padded
    __shared__ float alpha[32];
    __shared__ float red[2][256];

    if (b == 0)
        for (int i = tid; i < 1024; i += 256) out_trans[i] = trans[i];
    for (int i = tid; i < 1024; i += 256) {
        int ii = i >> 5, jj = i & 31;
        tT[jj * 33 + ii] = trans[i];
    }
    const int len = lengths[b];
    const float* lg = logits + (size_t)b * Sdim * Cdim;
    const int*   tg = targets + b * Sdim;

    float u = 0.0f, bs = 0.0f;
    for (int t = tid; t < Sdim; t += 256) {
        if (t < len) {
            u += lg[t * 32 + tg[t]];
            if (t >= 1) bs += trans[tg[t - 1] * 32 + tg[t]];
        }
    }
    red[0][tid] = u; red[1][tid] = bs;
    __syncthreads();
    for (int off = 128; off > 0; off >>= 1) {
        if (tid < off) {
            red[0][tid] += red[0][tid + off];
            red[1][tid] += red[1][tid + off];
        }
        __syncthreads();
    }

    if (tid < 32) alpha[tid] = lg[tid];
    float trow[32];
    if (tid < 32) {
        #pragma unroll
        for (int i = 0; i < 32; ++i) trow[i] = tT[tid * 33 + i];
    }
    __syncthreads();

    float lcur = 0.0f;
    if (tid < 32 && len > 1) lcur = lg[32 + tid];
    for (int t = 1; t < len; ++t) {
        float nv = 0.0f, lnxt = 0.0f;
        if (tid < 32) {
            if (t + 1 < len) lnxt = lg[(t + 1) * 32 + tid];   // prefetch
            float m = -3.0e38f;
            #pragma unroll
            for (int i = 0; i < 32; ++i) m = fmaxf(m, alpha[i] + trow[i]);
            float s = 0.0f;
            #pragma unroll
            for (int i = 0; i < 32; ++i) s += __expf(alpha[i] + trow[i] - m);
            nv = m + __logf(s) + lcur;
        }
        __syncthreads();
        if (tid < 32) alpha[tid] = nv;
        __syncthreads();
        lcur = lnxt;
    }
    if (tid == 0) {
        float m = -3.0e38f;
        for (int j = 0; j < 32; ++j) m = fmaxf(m, alpha[j]);
        float s = 0.0f;
        for (int j = 0; j < 32; ++j) s += __expf(alpha[j] - m);
        out_ll[b] = red[0][0] + red[1][0] - (m + __logf(s));
    }
}

// ---------------------------------------------------------------------------
extern "C" void kernel_launch(void* const* d_in, const int* in_sizes, int n_in,
                              void* d_out, int out_size, void* d_ws, size_t ws_size,
                              hipStream_t stream) {
    (void)in_sizes; (void)n_in; (void)out_size; (void)ws_size;
    const int*   tokens  = (const int*)d_in[0];
    const int*   lengths = (const int*)d_in[1];
    const int*   targets = (const int*)d_in[2];
    const float* emb     = (const float*)d_in[3];
    const float* Wf      = (const float*)d_in[4];
    const float* Uf      = (const float*)d_in[5];
    const float* bf_     = (const float*)d_in[6];
    const float* Wb      = (const float*)d_in[7];
    const float* Ub      = (const float*)d_in[8];
    const float* bb_     = (const float*)d_in[9];
    const float* Wd      = (const float*)d_in[10];
    const float* bd      = (const float*)d_in[11];
    const float* trans   = (const float*)d_in[12];

    float* out_logits = (float*)d_out;                 // 1048576
    float* out_ll     = out_logits + 1048576;          // 64
    float* out_trans  = out_ll + 64;                   // 1024

    // ws layout (~161 MiB, unchanged):
    //   [0, 1MB)              ushort upk8[2][32][1024][8]   (f16 U chunks)
    //   [1MB, 1MB+128MB)      ushort xp [2][NROW][1024]     (f16)
    //   [.., +32MB)           ushort hall[NROW][512]        (f16)
    // embp (18MB) + Wp (1.2MB) live INSIDE the hall region: they are only
    // needed until k_xproj finishes; k_lstm overwrites hall afterwards.
    char* ws = (char*)d_ws;
    unsigned short* upk8 = (unsigned short*)ws;
    unsigned short* xp   = (unsigned short*)(ws + (1u << 20));
    char*           hreg = ws + (1u << 20) + (size_t)2 * NROW * G4 * 2;
    unsigned short* hall = (unsigned short*)hreg;
    unsigned int*   embp = (unsigned int*)hreg;                       // 18.0 MB
    unsigned int*   Wp   = (unsigned int*)(hreg + (size_t)Vdim * EPAIR * 4); // 1.2 MB

    const size_t lstm_dyn_lds = (size_t)USTAGE * 1024 * 8 * 2;        // 147456 B

    k_pack_u8 <<<dim3(256), dim3(256), 0, stream>>>(Uf, Ub, upk8);
    k_pack_emb<<<dim3((Vdim * EPAIR + 255) / 256), dim3(256), 0, stream>>>(emb, embp);
    k_pack_w  <<<dim3((2 * EPAIR * 1024 + 255) / 256), dim3(256), 0, stream>>>(Wf, Wb, Wp);
    k_xproj   <<<dim3(NROW / 32, 8), dim3(256), 0, stream>>>(tokens, embp, Wp, bf_, bb_, xp);
    k_lstm    <<<dim3(128), dim3(1024), lstm_dyn_lds, stream>>>(upk8, xp, hall);
    k_dense   <<<dim3(NROW / 8), dim3(256), 0, stream>>>(hall, Wd, bd, out_logits);
    k_crf     <<<dim3(64), dim3(256), 0, stream>>>(out_logits, targets, lengths, trans, out_ll, out_trans);
}

// Round 6
// 1570.905 us; speedup vs baseline: 1.5672x; 1.0318x over previous
//
#include <hip/hip_runtime.h>

// Problem dims
#define Bdim 64
#define Sdim 512
#define Vdim 30000
#define Edim 300
#define Hdim 256
#define Cdim 32
#define G4   1024     // 4*H
#define NROW 32768    // B*S
#define KQ   32       // 256 k-values / 8 per 16B chunk
#define USTAGE 9      // kq-blocks of U staged in DYNAMIC LDS (144 KB)
#define RKQ    20     // kq-blocks of U staged in VGPRs (80 regs; budget 128
                      // via amdgpu_waves_per_eu(4,4) — r3/r4 failed because
                      // the allocator targeted 2 blocks/CU = 64-VGPR cap)
#define EPAIR  (Edim / 2)   // 150 f16-pairs along E
#define XLSTR  152          // padded LDS row stride (uints) for 8B alignment

// ---------- f16 helpers (store as plain ushort to avoid ABI surprises) -----
typedef _Float16 half2v __attribute__((ext_vector_type(2)));

__device__ __forceinline__ unsigned short f2h_bits(float f) {
    union { _Float16 h; unsigned short u; } v; v.h = (_Float16)f; return v.u;
}
__device__ __forceinline__ float h2f(unsigned short u) {
    union { _Float16 h; unsigned short u; } v; v.u = u; return (float)v.h;
}
__device__ __forceinline__ unsigned int pack2h(float lo, float hi) {
    return (unsigned int)f2h_bits(lo) | ((unsigned int)f2h_bits(hi) << 16);
}
__device__ __forceinline__ float sigf(float x) { return 1.0f / (1.0f + __expf(-x)); }
__device__ __forceinline__ float tanhfast(float x) { return 2.0f / (1.0f + __expf(-2.0f * x)) - 1.0f; }

// 2 MACs from packed f16 pairs, f32 accumulate (v_dot2_f32_f16 when available)
__device__ __forceinline__ float dot2(unsigned int u, unsigned int h, float acc) {
#if __has_builtin(__builtin_amdgcn_fdot2)
    union { unsigned int i; half2v h; } a, b; a.i = u; b.i = h;
    return __builtin_amdgcn_fdot2(a.h, b.h, acc, false);
#else
    acc = fmaf(h2f((unsigned short)(u & 0xffffu)), h2f((unsigned short)(h & 0xffffu)), acc);
    return fmaf(h2f((unsigned short)(u >> 16)), h2f((unsigned short)(h >> 16)), acc);
#endif
}
// 8 MACs from one 16B U chunk and one 16B h chunk (two independent chains)
__device__ __forceinline__ void dot8(float& a0, float& a1, uint4 uv, uint4 hv) {
    a0 = dot2(uv.x, hv.x, a0);
    a1 = dot2(uv.y, hv.y, a1);
    a0 = dot2(uv.z, hv.z, a0);
    a1 = dot2(uv.w, hv.w, a1);
}

// ---------- K0a: pack U (f32 [256][1024]) -> f16 chunks [2][32][1024][8] ----
__global__ __launch_bounds__(256) void k_pack_u8(
    const float* __restrict__ Uf, const float* __restrict__ Ub,
    unsigned short* __restrict__ upk8)
{
    int idx = blockIdx.x * 256 + threadIdx.x;   // 0 .. 65535
    if (idx >= 2 * KQ * 1024) return;
    int dir = idx >> 15;
    int rem = idx & 32767;
    int kq  = rem >> 10;
    int n   = rem & 1023;
    const float* U = dir ? Ub : Uf;
    unsigned int w[4];
    #pragma unroll
    for (int p = 0; p < 4; ++p)
        w[p] = pack2h(U[(8 * kq + 2 * p) * G4 + n], U[(8 * kq + 2 * p + 1) * G4 + n]);
    uint4 o = make_uint4(w[0], w[1], w[2], w[3]);
    *(uint4*)&upk8[(size_t)idx * 8] = o;
}

// ---------- K0b: pack emb f32 [V][300] -> f16 pairs [V*150] uints -----------
__global__ __launch_bounds__(256) void k_pack_emb(
    const float* __restrict__ emb, unsigned int* __restrict__ embp)
{
    int p = blockIdx.x * 256 + threadIdx.x;     // flat pair index
    if (p >= Vdim * EPAIR) return;
    float2 v = *(const float2*)&emb[(size_t)2 * p];
    embp[p] = pack2h(v.x, v.y);
}

// ---------- K0c: pack W f32 [300][1024] -> f16 k-pairs [2][150][1024] -------
__global__ __launch_bounds__(256) void k_pack_w(
    const float* __restrict__ Wf, const float* __restrict__ Wb,
    unsigned int* __restrict__ Wp)
{
    int idx = blockIdx.x * 256 + threadIdx.x;   // 0 .. 2*150*1024-1
    if (idx >= 2 * EPAIR * 1024) return;
    int dir = idx / (EPAIR * 1024);
    int rem = idx - dir * (EPAIR * 1024);
    int kp  = rem >> 10;
    int n   = rem & 1023;
    const float* W = dir ? Wb : Wf;
    Wp[idx] = pack2h(W[(2 * kp) * G4 + n], W[(2 * kp + 1) * G4 + n]);
}

// ---------- K1: xproj = emb[tokens] @ W + bias  -> f16 [2][NROW][1024] ------
// grid (NROW/32, 8), block 256. BOTH dirs per block. Each thread owns 4
// CONSECUTIVE cols -> W reads are dwordx4 (4x fewer VMEM instr), stores
// are ushort4.
__global__ __launch_bounds__(256) void k_xproj(
    const int* __restrict__ tokens, const unsigned int* __restrict__ embp,
    const unsigned int* __restrict__ Wp,
    const float* __restrict__ bf_, const float* __restrict__ bb_,
    unsigned short* __restrict__ xp)
{
    __shared__ unsigned int xl[32 * XLSTR];    // 19456 B, f16 pairs
    const int m0  = blockIdx.x * 32;
    const int tid = threadIdx.x;

    for (int i = tid; i < 32 * EPAIR; i += 256) {
        int r = i / EPAIR, kp = i - r * EPAIR;
        int tok = tokens[m0 + r];
        xl[r * XLSTR + kp] = embp[(size_t)tok * EPAIR + kp];
    }
    __syncthreads();

    const int tx = tid & 31, ty = tid >> 5;          // ty: 8 groups of 4 rows
    const int c0 = blockIdx.y * 128 + tx * 4;        // 4 consecutive cols
    float bj[2][4];
    #pragma unroll
    for (int j = 0; j < 4; ++j) {
        bj[0][j] = bf_[c0 + j];
        bj[1][j] = bb_[c0 + j];
    }
    float acc[2][4][4] = {};

    for (int kp = 0; kp < EPAIR; kp += 2) {          // 150 = 75*2 exact
        uint2 xv[4];
        #pragma unroll
        for (int i = 0; i < 4; ++i)
            xv[i] = *(const uint2*)&xl[(ty * 4 + i) * XLSTR + kp];
        #pragma unroll
        for (int kk = 0; kk < 2; ++kk) {
            #pragma unroll
            for (int d = 0; d < 2; ++d) {
                uint4 wv = *(const uint4*)(Wp + (size_t)d * EPAIR * 1024
                                              + (size_t)(kp + kk) * 1024 + c0);
                #pragma unroll
                for (int i = 0; i < 4; ++i) {
                    unsigned int xpair = kk ? xv[i].y : xv[i].x;
                    acc[d][i][0] = dot2(wv.x, xpair, acc[d][i][0]);
                    acc[d][i][1] = dot2(wv.y, xpair, acc[d][i][1]);
                    acc[d][i][2] = dot2(wv.z, xpair, acc[d][i][2]);
                    acc[d][i][3] = dot2(wv.w, xpair, acc[d][i][3]);
                }
            }
        }
    }
    #pragma unroll
    for (int d = 0; d < 2; ++d) {
        size_t base = (size_t)d * NROW * G4;
        #pragma unroll
        for (int i = 0; i < 4; ++i) {
            size_t row = (size_t)(m0 + ty * 4 + i) * G4;
            ushort4 o;
            o.x = f2h_bits(acc[d][i][0] + bj[d][0]);
            o.y = f2h_bits(acc[d][i][1] + bj[d][1]);
            o.z = f2h_bits(acc[d][i][2] + bj[d][2]);
            o.w = f2h_bits(acc[d][i][3] + bj[d][3]);
            *(ushort4*)&xp[base + row + c0] = o;
        }
    }
}

// ---------- K2: LSTM recurrence, v7 ----------------------------------------
// 128 WGs = (dir, batch), 1024 threads, EXACTLY 4 waves/EU (1 WG/CU) so the
// allocator gets the full 128-VGPR budget. Thread n owns column n.
// U kq-blocks: [0,9) in 144KB dynamic LDS, [9,29) in VGPRs (RKQ=20),
// remaining 3 streamed from L2 (48 KB/step).
__global__ __launch_bounds__(1024)
__attribute__((amdgpu_waves_per_eu(4, 4)))
void k_lstm(
    const unsigned short* __restrict__ upk8,   // [2][KQ][1024][8] f16
    const unsigned short* __restrict__ xp,     // [2][NROW][1024]  f16
    unsigned short* __restrict__ hout)         // [NROW][512] f16 = [hf|hb]
{
    const int bx  = blockIdx.x;
    const int dir = bx >> 6;
    const int b   = bx & 63;
    const int n   = threadIdx.x;               // 0..1023
    const int gi  = n >> 8;                    // gate: 0=i 1=f 2=g 3=o
    const unsigned short* __restrict__ Uq = upk8 + (size_t)dir * (KQ * 1024 * 8);
    const unsigned short* __restrict__ xpd =
        xp + (size_t)dir * NROW * G4 + (size_t)b * Sdim * G4;

    __shared__ float          abuf[1024];                   // 4 KB gates
    __shared__ __align__(16) unsigned short hl[256];        // f16 h
    extern __shared__ __align__(16) unsigned short ust[];   // 144 KB (kq 0..8)

    {   // vectorized one-time LDS stage of U kq-blocks [0,USTAGE)
        const uint4* src = (const uint4*)Uq;
        uint4*       dst = (uint4*)ust;
        for (int i = n; i < USTAGE * 1024; i += 1024) dst[i] = src[i];
    }
    // register-stage U kq-blocks [USTAGE, USTAGE+RKQ) — step-invariant
    uint4 ur[RKQ];
    #pragma unroll
    for (int r = 0; r < RKQ; ++r)
        ur[r] = *(const uint4*)&Uq[((size_t)(USTAGE + r) * 1024 + n) * 8];

    if (n < 256) hl[n] = 0;
    float c = 0.0f;
    __syncthreads();

    for (int step = 0; step < Sdim; ++step) {
        const int t = dir ? (Sdim - 1 - step) : step;
        float zx = h2f(xpd[(size_t)t * G4 + n]);   // issued early, used late
        float a0 = 0.0f, a1 = 0.0f;
        // streamed-from-L2 blocks (issue loads first; compiler pipelines)
        #pragma unroll
        for (int kq = USTAGE + RKQ; kq < KQ; ++kq) {
            uint4 uv = *(const uint4*)&Uq[((size_t)kq * 1024 + n) * 8];
            uint4 hv = *(const uint4*)&hl[kq * 8];
            dot8(a0, a1, uv, hv);
        }
        // register-staged blocks
        #pragma unroll
        for (int r = 0; r < RKQ; ++r) {
            uint4 hv = *(const uint4*)&hl[(USTAGE + r) * 8];
            dot8(a0, a1, ur[r], hv);
        }
        // LDS-staged blocks
        #pragma unroll
        for (int kq = 0; kq < USTAGE; ++kq) {
            uint4 uv = *(const uint4*)&ust[(kq * 1024 + n) * 8];
            uint4 hv = *(const uint4*)&hl[kq * 8];
            dot8(a0, a1, uv, hv);
        }
        float z = zx + a0 + a1;
        float a = (gi == 2) ? tanhfast(z) : sigf(z);
        abuf[n] = a;
        __syncthreads();               // abuf complete; all hl readers done
        if (n < 256) {
            float iv = abuf[n];
            float fv = abuf[n + 256];
            float gv = abuf[n + 512];
            float ov = abuf[n + 768];
            c = fv * c + iv * gv;
            float hn = ov * tanhfast(c);
            unsigned short hb = f2h_bits(hn);
            hl[n] = hb;
            hout[((size_t)(b * Sdim + t)) * 512 + dir * 256 + n] = hb;
        }
        __syncthreads();               // hl ready for next step
    }
}

// ---------- K3: logits = [hf|hb] @ Wd + bd -> d_out[0:1048576] --------------
__global__ __launch_bounds__(256) void k_dense(
    const unsigned short* __restrict__ hall, const float* __restrict__ Wd,
    const float* __restrict__ bd, float* __restrict__ outL)
{
    __shared__ float wl[256 * 32];    // 32 KB
    __shared__ float hlr[8 * 512];    // 16 KB
    const int r0  = blockIdx.x * 8;
    const int tid = threadIdx.x;
    for (int i = tid; i < 8 * 512; i += 256)
        hlr[i] = h2f(hall[(size_t)r0 * 512 + i]);
    const int tx = tid & 31, ty = tid >> 5;
    float acc = 0.0f;
    for (int half = 0; half < 2; ++half) {
        __syncthreads();   // prior readers done (also covers hlr stores)
        for (int i = tid; i < 256 * 32; i += 256) wl[i] = Wd[half * 8192 + i];
        __syncthreads();
        const float* hrow = hlr + ty * 512 + half * 256;
        #pragma unroll 8
        for (int k = 0; k < 256; ++k)
            acc = fmaf(hrow[k], wl[k * 32 + tx], acc);
    }
    outL[(size_t)(r0 + ty) * 32 + tx] = acc + bd[tx];
}

// ---------- K4: CRF log-likelihood + trans passthrough ----------------------
__global__ __launch_bounds__(256) void k_crf(
    const float* __restrict__ logits, const int* __restrict__ targets,
    const int* __restrict__ lengths, const float* __restrict__ trans,
    float* __restrict__ out_ll, float* __restrict__ out_trans)
{
    const int b   = blockIdx.x;
    const int tid = threadIdx.x;
    __shared__ float tT[32 * 33];     // trans transposed, padded
    __shared__ float alpha[32];
    __shared__ float red[2][256];

    if (b == 0)
        for (int i = tid; i < 1024; i += 256) out_trans[i] = trans[i];
    for (int i = tid; i < 1024; i += 256) {
        int ii = i >> 5, jj = i & 31;
        tT[jj * 33 + ii] = trans[i];
    }
    const int len = lengths[b];
    const float* lg = logits + (size_t)b * Sdim * Cdim;
    const int*   tg = targets + b * Sdim;

    float u = 0.0f, bs = 0.0f;
    for (int t = tid; t < Sdim; t += 256) {
        if (t < len) {
            u += lg[t * 32 + tg[t]];
            if (t >= 1) bs += trans[tg[t - 1] * 32 + tg[t]];
        }
    }
    red[0][tid] = u; red[1][tid] = bs;
    __syncthreads();
    for (int off = 128; off > 0; off >>= 1) {
        if (tid < off) {
            red[0][tid] += red[0][tid + off];
            red[1][tid] += red[1][tid + off];
        }
        __syncthreads();
    }

    if (tid < 32) alpha[tid] = lg[tid];
    float trow[32];
    if (tid < 32) {
        #pragma unroll
        for (int i = 0; i < 32; ++i) trow[i] = tT[tid * 33 + i];
    }
    __syncthreads();

    float lcur = 0.0f;
    if (tid < 32 && len > 1) lcur = lg[32 + tid];
    for (int t = 1; t < len; ++t) {
        float nv = 0.0f, lnxt = 0.0f;
        if (tid < 32) {
            if (t + 1 < len) lnxt = lg[(t + 1) * 32 + tid];   // prefetch
            float m = -3.0e38f;
            #pragma unroll
            for (int i = 0; i < 32; ++i) m = fmaxf(m, alpha[i] + trow[i]);
            float s = 0.0f;
            #pragma unroll
            for (int i = 0; i < 32; ++i) s += __expf(alpha[i] + trow[i] - m);
            nv = m + __logf(s) + lcur;
        }
        __syncthreads();
        if (tid < 32) alpha[tid] = nv;
        __syncthreads();
        lcur = lnxt;
    }
    if (tid == 0) {
        float m = -3.0e38f;
        for (int j = 0; j < 32; ++j) m = fmaxf(m, alpha[j]);
        float s = 0.0f;
        for (int j = 0; j < 32; ++j) s += __expf(alpha[j] - m);
        out_ll[b] = red[0][0] + red[1][0] - (m + __logf(s));
    }
}

// ---------------------------------------------------------------------------
extern "C" void kernel_launch(void* const* d_in, const int* in_sizes, int n_in,
                              void* d_out, int out_size, void* d_ws, size_t ws_size,
                              hipStream_t stream) {
    (void)in_sizes; (void)n_in; (void)out_size; (void)ws_size;
    const int*   tokens  = (const int*)d_in[0];
    const int*   lengths = (const int*)d_in[1];
    const int*   targets = (const int*)d_in[2];
    const float* emb     = (const float*)d_in[3];
    const float* Wf      = (const float*)d_in[4];
    const float* Uf      = (const float*)d_in[5];
    const float* bf_     = (const float*)d_in[6];
    const float* Wb      = (const float*)d_in[7];
    const float* Ub      = (const float*)d_in[8];
    const float* bb_     = (const float*)d_in[9];
    const float* Wd      = (const float*)d_in[10];
    const float* bd      = (const float*)d_in[11];
    const float* trans   = (const float*)d_in[12];

    float* out_logits = (float*)d_out;                 // 1048576
    float* out_ll     = out_logits + 1048576;          // 64
    float* out_trans  = out_ll + 64;                   // 1024

    // ws layout (~161 MiB, unchanged):
    //   [0, 1MB)              ushort upk8[2][32][1024][8]   (f16 U chunks)
    //   [1MB, 1MB+128MB)      ushort xp [2][NROW][1024]     (f16)
    //   [.., +32MB)           ushort hall[NROW][512]        (f16)
    // embp (18MB) + Wp (1.2MB) live INSIDE the hall region: they are only
    // needed until k_xproj finishes; k_lstm overwrites hall afterwards.
    char* ws = (char*)d_ws;
    unsigned short* upk8 = (unsigned short*)ws;
    unsigned short* xp   = (unsigned short*)(ws + (1u << 20));
    char*           hreg = ws + (1u << 20) + (size_t)2 * NROW * G4 * 2;
    unsigned short* hall = (unsigned short*)hreg;
    unsigned int*   embp = (unsigned int*)hreg;                       // 18.0 MB
    unsigned int*   Wp   = (unsigned int*)(hreg + (size_t)Vdim * EPAIR * 4); // 1.2 MB

    const size_t lstm_dyn_lds = (size_t)USTAGE * 1024 * 8 * 2;        // 147456 B

    k_pack_u8 <<<dim3(256), dim3(256), 0, stream>>>(Uf, Ub, upk8);
    k_pack_emb<<<dim3((Vdim * EPAIR + 255) / 256), dim3(256), 0, stream>>>(emb, embp);
    k_pack_w  <<<dim3((2 * EPAIR * 1024 + 255) / 256), dim3(256), 0, stream>>>(Wf, Wb, Wp);
    k_xproj   <<<dim3(NROW / 32, 8), dim3(256), 0, stream>>>(tokens, embp, Wp, bf_, bb_, xp);
    k_lstm    <<<dim3(128), dim3(1024), lstm_dyn_lds, stream>>>(upk8, xp, hall);
    k_dense   <<<dim3(NROW / 8), dim3(256), 0, stream>>>(hall, Wd, bd, out_logits);
    k_crf     <<<dim3(64), dim3(256), 0, stream>>>(out_logits, targets, lengths, trans, out_ll, out_trans);
}